// Round 14
// baseline (1451.965 us; speedup 1.0000x reference)
//
#include <hip/hip_runtime.h>

#define NBATCH 64
#define NCH    128
#define NTYPE  6
#define NK     127
#define N1     25
#define N2     50
#define N3     100
#define NAXIS  4
#define OUTPER 400  // N3*NAXIS
#define W2P    28   // k_mlp W2 row pad
#define W3P4   52   // k_mlp W3 f-row pad
#define Y2ROW  28   // y2t half-row stride: 112B, 16B-aligned, 8 bank-starts
#define MAXKP  152
#define MAXC4  38

// ---------- repetition macros: straight-line code, literal indices ONLY ----------
#define R4(M)  M(0) M(1) M(2) M(3)
#define R5(M)  M(0) M(1) M(2) M(3) M(4)
#define R6(M)  M(0) M(1) M(2) M(3) M(4) M(5)
#define R7(M)  M(0) M(1) M(2) M(3) M(4) M(5) M(6)
#define R12(M) M(0) M(1) M(2) M(3) M(4) M(5) M(6) M(7) M(8) M(9) M(10) M(11)
#define R25(M) M(0) M(1) M(2) M(3) M(4) M(5) M(6) M(7) M(8) M(9) M(10) M(11) M(12) \
               M(13) M(14) M(15) M(16) M(17) M(18) M(19) M(20) M(21) M(22) M(23) M(24)
#define R25A(M,a) M(a,0) M(a,1) M(a,2) M(a,3) M(a,4) M(a,5) M(a,6) M(a,7) M(a,8) M(a,9) \
               M(a,10) M(a,11) M(a,12) M(a,13) M(a,14) M(a,15) M(a,16) M(a,17) M(a,18) \
               M(a,19) M(a,20) M(a,21) M(a,22) M(a,23) M(a,24)
#define R50(M) R25(M) M(25) M(26) M(27) M(28) M(29) M(30) M(31) M(32) M(33) M(34) \
               M(35) M(36) M(37) M(38) M(39) M(40) M(41) M(42) M(43) M(44) M(45) \
               M(46) M(47) M(48) M(49)

__device__ __forceinline__ float tanh_fast(float x) {
    float e = __expf(2.0f * x);
    return 1.0f - 2.0f * __builtin_amdgcn_rcpf(e + 1.0f);
}

__global__ void k_transpose(const float* __restrict__ coords, float* __restrict__ ct) {
    int t = blockIdx.x * blockDim.x + threadIdx.x;
    if (t >= NBATCH * NCH * 3) return;
    int b  = t & (NBATCH - 1);
    int jd = t >> 6;
    int d  = jd % 3;
    int j  = jd / 3;
    ct[t] = coords[(b * NCH + j) * 3 + d];
}

// padded counting sort: each 4-k chunk has ONE neighbor type; pads = -1.
__device__ __forceinline__ void sort_pad(
    const int* __restrict__ types, int n, int* tysh, int* ksp, int* chs, int* aux,
    int tid, int nthr)
{
    for (int t = tid; t < NCH; t += nthr) tysh[t] = types[t];
    __syncthreads();
    if (tid == 0) {
        int cnt[NTYPE], pos[NTYPE];
        for (int t = 0; t < NTYPE; ++t) cnt[t] = 0;
        for (int k = 0; k < NK; ++k) { int j = (k < n) ? k : k + 1; cnt[tysh[j]]++; }
        int c = 0;
        for (int t = 0; t < NTYPE; ++t) {
            pos[t] = c;
            int pc = (cnt[t] + 3) & ~3;
            for (int q = c >> 2; q < (c + pc) >> 2; ++q) chs[q] = t;
            for (int p = c + cnt[t]; p < c + pc; ++p) ksp[p] = -1;
            c += pc;
        }
        aux[0] = c >> 2;
        for (int k = 0; k < NK; ++k) { int j = (k < n) ? k : k + 1; ksp[pos[tysh[j]]++] = k; }
    }
    __syncthreads();
}

// Kernel A (r12/r13 version, proven): LDS-staged weights, lockstep chunks.
__global__ __launch_bounds__(256, 4) void k_mlp(
    const float* __restrict__ ct, const int* __restrict__ types,
    const float* __restrict__ W1, const float* __restrict__ B1,
    const float* __restrict__ W2, const float* __restrict__ B2,
    const float* __restrict__ W3, const float* __restrict__ B3,
    float* __restrict__ t1buf)
{
    __shared__ float w2s[N2 * W2P];
    __shared__ float w3s4[4 * W3P4];
    __shared__ float w1s[N1], b1s[N1], b2s[N2], b3s4[4];
    __shared__ int   ksp[MAXKP];
    __shared__ int   chs[MAXC4];
    __shared__ int   tysh[NCH];
    __shared__ int   aux[1];

    const int n   = blockIdx.x >> 2;
    const int qc  = blockIdx.x & 3;
    const int w   = threadIdx.x >> 6;
    const int b   = threadIdx.x & 63;
    const int tid = threadIdx.x;

    sort_pad(types, n, tysh, ksp, chs, aux, tid, 256);
    const int nch4 = __builtin_amdgcn_readfirstlane(aux[0]);
    const int c_lo = (qc * nch4) >> 2;
    const int c_hi = ((qc + 1) * nch4) >> 2;

    const int tn = __builtin_amdgcn_readfirstlane(tysh[n]);
    const float cx = ct[(n*3+0)*NBATCH + b];
    const float cy = ct[(n*3+1)*NBATCH + b];
    const float cz = ct[(n*3+2)*NBATCH + b];

    float t1a[12];
#define TIN(i) t1a[i] = 0.0f;
    R12(TIN)
#undef TIN

    int prevty = -1;
    for (int kc = c_lo; kc < c_hi; ++kc) {
        const int tj = __builtin_amdgcn_readfirstlane(chs[kc]);
        const int ch = tn * NTYPE + tj;
        if (tj != prevty) {
            __syncthreads();
            for (int idx = tid; idx < N2*N1; idx += 256)
                w2s[(idx / N1) * W2P + (idx % N1)] = W2[ch*(N2*N1) + idx];
            for (int idx = tid; idx < 4*N2; idx += 256)
                w3s4[(idx / N2) * W3P4 + (idx % N2)] = W3[ch*(N3*N2) + idx];
            if (tid < N1) { w1s[tid] = W1[ch*N1+tid]; b1s[tid] = B1[ch*N1+tid]; }
            if (tid < N2) b2s[tid] = B2[ch*N2+tid];
            if (tid < 4)  b3s4[tid] = B3[ch*N3+tid];
            prevty = tj;
            __syncthreads();
        }
        const int sk = __builtin_amdgcn_readfirstlane(ksp[kc*4 + w]);
        if (sk < 0) continue;
        const int j = (sk < n) ? sk : sk + 1;

        const float dx = cx - ct[(j*3+0)*NBATCH + b];
        const float dy = cy - ct[(j*3+1)*NBATCH + b];
        const float dz = cz - ct[(j*3+2)*NBATCH + b];
        const float d2 = dx*dx + dy*dy + dz*dz;
        const float dd = sqrtf(d2);
        const float dinv = __builtin_amdgcn_rcpf(fmaxf(dd, 1e-12f));
        const float di2 = dinv * dinv;
        const float ax = dx * di2, ay = dy * di2, az = dz * di2;

        float y1[N1];
#define L1S(o) y1[o] = tanh_fast(fmaf(dinv, w1s[o], b1s[o]));
        R25(L1S)
#undef L1S

        float zf0 = b3s4[0], zf1 = b3s4[1], zf2 = b3s4[2], zf3 = b3s4[3];
        float r[4];
#define P1Q(o,q) { float4 wq = *(const float4*)&w2s[(o)*W2P + (q)*4]; \
                   z = fmaf(wq.x, y1[(q)*4+0], z); z = fmaf(wq.y, y1[(q)*4+1], z); \
                   z = fmaf(wq.z, y1[(q)*4+2], z); z = fmaf(wq.w, y1[(q)*4+3], z); }
#define MLP2(o) { float z = b2s[o]; \
                  P1Q(o,0) P1Q(o,1) P1Q(o,2) P1Q(o,3) P1Q(o,4) P1Q(o,5) \
                  z = fmaf(w2s[(o)*W2P + 24], y1[24], z); \
                  float y2o = tanh_fast(z) + y1[(o)%N1]; \
                  if ((o) < 4) r[(o)&3] = y2o; \
                  zf0 = fmaf(w3s4[0*W3P4+(o)], y2o, zf0); \
                  zf1 = fmaf(w3s4[1*W3P4+(o)], y2o, zf1); \
                  zf2 = fmaf(w3s4[2*W3P4+(o)], y2o, zf2); \
                  zf3 = fmaf(w3s4[3*W3P4+(o)], y2o, zf3); }
        R50(MLP2)
#undef MLP2
#undef P1Q

#define O4F(f) { float o4 = tanh_fast(f==0?zf0:f==1?zf1:f==2?zf2:zf3) + r[f]; \
        t1a[0+(f)] = fmaf(ax, o4, t1a[0+(f)]); \
        t1a[4+(f)] = fmaf(ay, o4, t1a[4+(f)]); \
        t1a[8+(f)] = fmaf(az, o4, t1a[8+(f)]); }
        O4F(0) O4F(1) O4F(2) O4F(3)
#undef O4F
    }

    float* dst = t1buf + (n * 12) * NBATCH + b;
#define TAT(i) atomicAdd(dst + (i) * NBATCH, t1a[i]);
    R12(TAT)
#undef TAT
}

// Kernel B: block=(n,gh,kh), 512 thr, (512,4) = the proven 64-VGPR point.
// LDS DECONGESTION (r11 was LDS-issue-bound: ~3900 LDS insts/chunk/block):
//  - P1 weights via wave-uniform s_load (scalar pipe, K$-hot from sort_pad)
//    instead of LDS broadcast reads (-175 insts/wave-k)
//  - y2t b-major [kk][h][b][28]: P1 6xb128+1 writes, P2 12xb128+2 reads per k
//    (28-dword stride: 16B-aligned, 8 bank-starts -> conflict-uniform)
//  - pad-k slots write zeros (t2=0) so P2 runs guard-free
// 2 blocks/CU (2 x 62.7 KB LDS <= 160 KB).
__global__ __launch_bounds__(512, 4) void k_res2(
    const float* __restrict__ ct, const int* __restrict__ types,
    const float* __restrict__ W1, const float* __restrict__ B1,
    const float* __restrict__ W2, const float* __restrict__ B2,
    const float* __restrict__ W3, const float* __restrict__ B3,
    const float* __restrict__ t1buf, float* __restrict__ out)
{
    __shared__ float y2t[4 * 2 * NBATCH * Y2ROW];  // 57344 B
    __shared__ float t2s[4 * NBATCH * NAXIS];      //  4096 B
    __shared__ int   ksp[MAXKP];
    __shared__ int   chs[MAXC4];
    __shared__ int   tysh[NCH];
    __shared__ int   aux[1];

    const int n    = blockIdx.x >> 2;
    const int gh   = (blockIdx.x >> 1) & 1;
    const int kh   = blockIdx.x & 1;
    const int w    = threadIdx.x >> 6;
    const int lane = threadIdx.x & 63;
    const int kk2  = w >> 1;                      // phase-1 k of chunk
    const int h    = w & 1;                       // phase-1 y2 half
    const int tid  = threadIdx.x;

    sort_pad(types, n, tysh, ksp, chs, aux, tid, 512);
    const int nch4 = __builtin_amdgcn_readfirstlane(aux[0]);
    const int c_lo = kh ? (nch4 >> 1) : 0;
    const int c_hi = kh ? nch4 : (nch4 >> 1);

    const int tn = __builtin_amdgcn_readfirstlane(tysh[n]);

    float t1r[12];
#define T1L(i) t1r[i] = t1buf[(n*12 + (i))*NBATCH + lane];
    R12(T1L)
#undef T1L

    const int g0 = __builtin_amdgcn_readfirstlane(w * 7);   // local g within half
    int gg[7], rh[7], ri[7];
#define GGI(gi) { int gl = ((g0 + (gi)) < N2) ? (g0 + (gi)) : (N2 - 1); \
                  gg[gi] = gh * N2 + gl; \
                  rh[gi] = (gl >= N1) ? 1 : 0; \
                  ri[gi] = gl - rh[gi] * N1; }
    R7(GGI)
#undef GGI

    float racc[7][4];
#define RIN(gi) racc[gi][0]=0.f; racc[gi][1]=0.f; racc[gi][2]=0.f; racc[gi][3]=0.f;
    R7(RIN)
#undef RIN

    for (int kc = c_lo; kc < c_hi; ++kc) {
        const int ch = tn * NTYPE + __builtin_amdgcn_readfirstlane(chs[kc]);
        float b3v[7];
#define B3L(gi) b3v[gi] = B3[ch*N3 + gg[gi]];
        R7(B3L)
#undef B3L
        const int kb = kc * 4;
        // ===== phase 1: stage y2 (b128 writes) + t2; weights via s_load =====
        {
            const int sk = __builtin_amdgcn_readfirstlane(ksp[kb + kk2]);
            float* y2w = &y2t[((kk2*2 + h)*NBATCH + lane)*Y2ROW];
            if (sk >= 0) {
                const int j = (sk < n) ? sk : sk + 1;
                const float dx = ct[(n*3+0)*NBATCH + lane] - ct[(j*3+0)*NBATCH + lane];
                const float dy = ct[(n*3+1)*NBATCH + lane] - ct[(j*3+1)*NBATCH + lane];
                const float dz = ct[(n*3+2)*NBATCH + lane] - ct[(j*3+2)*NBATCH + lane];
                const float d2 = dx*dx + dy*dy + dz*dz;
                const float dd = sqrtf(d2);
                const float dinv = __builtin_amdgcn_rcpf(fmaxf(dd, 1e-12f));

                if (h == 0) {
                    const float di2 = dinv * dinv;
                    const float ax = dx * di2, ay = dy * di2, az = dz * di2;
                    float4 t2v;
                    t2v.x = ax*t1r[0] + ay*t1r[4]  + az*t1r[8];
                    t2v.y = ax*t1r[1] + ay*t1r[5]  + az*t1r[9];
                    t2v.z = ax*t1r[2] + ay*t1r[6]  + az*t1r[10];
                    t2v.w = ax*t1r[3] + ay*t1r[7]  + az*t1r[11];
                    *(float4*)&t2s[(kk2*NBATCH + lane)*NAXIS] = t2v;
                }

                const float* w1r = W1 + ch * N1;      // wave-uniform -> s_load
                const float* b1r = B1 + ch * N1;
                float y1[N1];
#define L1S(o) y1[o] = tanh_fast(fmaf(dinv, w1r[o], b1r[o]));
                R25(L1S)
#undef L1S
                const float* w2h = W2 + ch * (N2*N1) + h * (N1*N1);
                const float* b2h = B2 + ch * N2 + h * N1;
#define P1I(oi,i) z = fmaf(w2h[(oi)*N1+(i)], y1[i], z);
#define P1ROW(oi) ({ float z = b2h[oi]; R25A(P1I,oi) tanh_fast(z) + y1[oi]; })
#define P1QUAD(q) { float4 v; \
                    v.x = P1ROW((q)*4+0); v.y = P1ROW((q)*4+1); \
                    v.z = P1ROW((q)*4+2); v.w = P1ROW((q)*4+3); \
                    *(float4*)&y2w[(q)*4] = v; }
                R6(P1QUAD)
                y2w[24] = P1ROW(24);
#undef P1QUAD
#undef P1ROW
#undef P1I
            } else {
                const float4 z4 = make_float4(0.f, 0.f, 0.f, 0.f);
#define ZQ(q) *(float4*)&y2w[(q)*4] = z4;
                R6(ZQ)
#undef ZQ
                y2w[24] = 0.f;
                if (h == 0) *(float4*)&t2s[(kk2*NBATCH + lane)*NAXIS] = z4;
            }
        }
        __syncthreads();
        // ===== phase 2: layer 3 (b128 y2 reads, SGPR weights), guard-free =====
        const float* w3b = W3 + ch * (N3*N2);
        for (int kp = 0; kp < 2; ++kp) {
            const int kkA = kp*2 + 0, kkB = kp*2 + 1;
            const float* yA0 = &y2t[((kkA*2+0)*NBATCH + lane)*Y2ROW];
            const float* yA1 = &y2t[((kkA*2+1)*NBATCH + lane)*Y2ROW];
            const float* yB0 = &y2t[((kkB*2+0)*NBATCH + lane)*Y2ROW];
            const float* yB1 = &y2t[((kkB*2+1)*NBATCH + lane)*Y2ROW];
            float zA[7], zB[7];
#define ZIN(gi) zA[gi] = b3v[gi]; zB[gi] = b3v[gi];
            R7(ZIN)
#undef ZIN
#define PW(gi) { const float* wr = w3b + gg[gi]*N2 + ioff + q4; \
                 const float l0 = wr[0], l1 = wr[1], l2 = wr[2], l3 = wr[3]; \
                 zA[gi] = fmaf(l0,va.x, fmaf(l1,va.y, fmaf(l2,va.z, fmaf(l3,va.w, zA[gi])))); \
                 zB[gi] = fmaf(l0,vb.x, fmaf(l1,vb.y, fmaf(l2,vb.z, fmaf(l3,vb.w, zB[gi])))); }
#define PQ(q) { const int q4 = (q)*4; \
                const float4 va = *(const float4*)&pA[q4]; \
                const float4 vb = *(const float4*)&pB[q4]; \
                R7(PW) }
            {   // half 0: i = 0..24
                const float* pA = yA0; const float* pB = yB0; const int ioff = 0;
                R6(PQ)
                const float ta = pA[24], tb = pB[24];
#define PT(gi) { const float lw = w3b[gg[gi]*N2 + ioff + 24]; \
                 zA[gi] = fmaf(lw, ta, zA[gi]); zB[gi] = fmaf(lw, tb, zB[gi]); }
                R7(PT)
#undef PT
            }
            {   // half 1: i = 25..49
                const float* pA = yA1; const float* pB = yB1; const int ioff = N1;
                R6(PQ)
                const float ta = pA[24], tb = pB[24];
#define PT(gi) { const float lw = w3b[gg[gi]*N2 + ioff + 24]; \
                 zA[gi] = fmaf(lw, ta, zA[gi]); zB[gi] = fmaf(lw, tb, zB[gi]); }
                R7(PT)
#undef PT
            }
#undef PQ
#undef PW
            const float4 t2vA = *(const float4*)&t2s[(kkA*NBATCH + lane)*NAXIS];
            const float4 t2vB = *(const float4*)&t2s[(kkB*NBATCH + lane)*NAXIS];
#define PFA(gi) { const float* rb = rh[gi] ? yA1 : yA0; \
                  const float o3 = tanh_fast(zA[gi]) + rb[ri[gi]]; \
                  racc[gi][0] = fmaf(o3, t2vA.x, racc[gi][0]); \
                  racc[gi][1] = fmaf(o3, t2vA.y, racc[gi][1]); \
                  racc[gi][2] = fmaf(o3, t2vA.z, racc[gi][2]); \
                  racc[gi][3] = fmaf(o3, t2vA.w, racc[gi][3]); }
            R7(PFA)
#undef PFA
#define PFB(gi) { const float* rb = rh[gi] ? yB1 : yB0; \
                  const float o3 = tanh_fast(zB[gi]) + rb[ri[gi]]; \
                  racc[gi][0] = fmaf(o3, t2vB.x, racc[gi][0]); \
                  racc[gi][1] = fmaf(o3, t2vB.y, racc[gi][1]); \
                  racc[gi][2] = fmaf(o3, t2vB.z, racc[gi][2]); \
                  racc[gi][3] = fmaf(o3, t2vB.w, racc[gi][3]); }
            R7(PFB)
#undef PFB
        }
        __syncthreads();
    }

#define PST(gi) if (g0 + (gi) < N2) { \
        float* dp = &out[(lane*NCH + n)*OUTPER + gg[gi]*NAXIS]; \
        atomicAdd(dp + 0, racc[gi][0]); \
        atomicAdd(dp + 1, racc[gi][1]); \
        atomicAdd(dp + 2, racc[gi][2]); \
        atomicAdd(dp + 3, racc[gi][3]); }
    R7(PST)
#undef PST
}

extern "C" void kernel_launch(void* const* d_in, const int* in_sizes, int n_in,
                              void* d_out, int out_size, void* d_ws, size_t ws_size,
                              hipStream_t stream) {
    const float* coords = (const float*)d_in[0];
    const int*   types  = (const int*)d_in[1];
    const float* W1 = (const float*)d_in[2];
    const float* B1 = (const float*)d_in[3];
    const float* W2 = (const float*)d_in[4];
    const float* B2 = (const float*)d_in[5];
    const float* W3 = (const float*)d_in[6];
    const float* B3 = (const float*)d_in[7];
    float* out = (float*)d_out;

    float* t1buf = (float*)d_ws;
    float* ct    = t1buf + NCH * 12 * NBATCH;

    hipMemsetAsync(t1buf, 0, (size_t)NCH * 12 * NBATCH * sizeof(float), stream);
    hipMemsetAsync(out, 0, (size_t)out_size * sizeof(float), stream);

    k_transpose<<<(NBATCH*NCH*3 + 255)/256, 256, 0, stream>>>(coords, ct);
    k_mlp <<<NCH*4, 256, 0, stream>>>(ct, types, W1,B1,W2,B2,W3,B3, t1buf);
    k_res2<<<NCH*4, 512, 0, stream>>>(ct, types, W1,B1,W2,B2,W3,B3, t1buf, out);
}

// Round 15
// 993.826 us; speedup vs baseline: 1.4610x; 1.4610x over previous
//
#include <hip/hip_runtime.h>

#define NBATCH 64
#define NCH    128
#define NTYPE  6
#define NK     127
#define N1     25
#define N2     50
#define N3     100
#define NAXIS  4
#define OUTPER 400  // N3*NAXIS
#define MAXKP  152
#define MAXC4  38

// ---------- repetition macros: straight-line code, literal indices ONLY ----------
#define R5(M)  M(0) M(1) M(2) M(3) M(4)
#define R7(M)  M(0) M(1) M(2) M(3) M(4) M(5) M(6)
#define R12(M) M(0) M(1) M(2) M(3) M(4) M(5) M(6) M(7) M(8) M(9) M(10) M(11)
#define R25(M) M(0) M(1) M(2) M(3) M(4) M(5) M(6) M(7) M(8) M(9) M(10) M(11) M(12) \
               M(13) M(14) M(15) M(16) M(17) M(18) M(19) M(20) M(21) M(22) M(23) M(24)
#define R25A(M,a) M(a,0) M(a,1) M(a,2) M(a,3) M(a,4) M(a,5) M(a,6) M(a,7) M(a,8) M(a,9) \
               M(a,10) M(a,11) M(a,12) M(a,13) M(a,14) M(a,15) M(a,16) M(a,17) M(a,18) \
               M(a,19) M(a,20) M(a,21) M(a,22) M(a,23) M(a,24)
#define R50(M) R25(M) M(25) M(26) M(27) M(28) M(29) M(30) M(31) M(32) M(33) M(34) \
               M(35) M(36) M(37) M(38) M(39) M(40) M(41) M(42) M(43) M(44) M(45) \
               M(46) M(47) M(48) M(49)

__device__ __forceinline__ float tanh_fast(float x) {
    float e = __expf(2.0f * x);                       // e^{2x}; inf/0 saturate correctly
    return 1.0f - 2.0f * __builtin_amdgcn_rcpf(e + 1.0f);
}

__global__ void k_transpose(const float* __restrict__ coords, float* __restrict__ ct) {
    int t = blockIdx.x * blockDim.x + threadIdx.x;
    if (t >= NBATCH * NCH * 3) return;
    int b  = t & (NBATCH - 1);
    int jd = t >> 6;
    int d  = jd % 3;
    int j  = jd / 3;
    ct[t] = coords[(b * NCH + j) * 3 + d];
}

// padded counting sort: each 4-k chunk has ONE neighbor type; pads = -1.
__device__ __forceinline__ void sort_pad(
    const int* __restrict__ types, int n, int* tysh, int* ksp, int* chs, int* aux,
    int tid, int nthr)
{
    for (int t = tid; t < NCH; t += nthr) tysh[t] = types[t];
    __syncthreads();
    if (tid == 0) {
        int cnt[NTYPE], pos[NTYPE];
        for (int t = 0; t < NTYPE; ++t) cnt[t] = 0;
        for (int k = 0; k < NK; ++k) { int j = (k < n) ? k : k + 1; cnt[tysh[j]]++; }
        int c = 0;
        for (int t = 0; t < NTYPE; ++t) {
            pos[t] = c;
            int pc = (cnt[t] + 3) & ~3;
            for (int q = c >> 2; q < (c + pc) >> 2; ++q) chs[q] = t;
            for (int p = c + cnt[t]; p < c + pc; ++p) ksp[p] = -1;
            c += pc;
        }
        aux[0] = c >> 2;
        for (int k = 0; k < NK; ++k) { int j = (k < n) ? k : k + 1; ksp[pos[tysh[j]]++] = k; }
    }
    __syncthreads();
}

// Kernel A: channel-uniform chunks (sort_pad), weights via wave-uniform s_load
// (scalar pipe, K$-hot because channel is fixed per chunk). No LDS weight
// staging: r13 arithmetic shows the LDS pipe is the bottleneck, and scalar
// loads run on a parallel pipe while freeing VGPRs.
__global__ __launch_bounds__(256, 4) void k_mlp(
    const float* __restrict__ ct, const int* __restrict__ types,
    const float* __restrict__ W1, const float* __restrict__ B1,
    const float* __restrict__ W2, const float* __restrict__ B2,
    const float* __restrict__ W3, const float* __restrict__ B3,
    float* __restrict__ t1buf)
{
    __shared__ int ksp[MAXKP];
    __shared__ int chs[MAXC4];
    __shared__ int tysh[NCH];
    __shared__ int aux[1];

    const int n   = blockIdx.x >> 2;
    const int qc  = blockIdx.x & 3;
    const int w   = threadIdx.x >> 6;
    const int b   = threadIdx.x & 63;
    const int tid = threadIdx.x;

    sort_pad(types, n, tysh, ksp, chs, aux, tid, 256);
    const int nch4 = __builtin_amdgcn_readfirstlane(aux[0]);
    const int c_lo = (qc * nch4) >> 2;
    const int c_hi = ((qc + 1) * nch4) >> 2;

    const int tn = __builtin_amdgcn_readfirstlane(tysh[n]);
    const float cx = ct[(n*3+0)*NBATCH + b];
    const float cy = ct[(n*3+1)*NBATCH + b];
    const float cz = ct[(n*3+2)*NBATCH + b];

    float t1a[12];
#define TIN(i) t1a[i] = 0.0f;
    R12(TIN)
#undef TIN

    for (int kc = c_lo; kc < c_hi; ++kc) {
        const int ch = tn * NTYPE + __builtin_amdgcn_readfirstlane(chs[kc]);
        const int sk = __builtin_amdgcn_readfirstlane(ksp[kc*4 + w]);
        if (sk < 0) continue;
        const int j = (sk < n) ? sk : sk + 1;

        const float dx = cx - ct[(j*3+0)*NBATCH + b];
        const float dy = cy - ct[(j*3+1)*NBATCH + b];
        const float dz = cz - ct[(j*3+2)*NBATCH + b];
        const float d2 = dx*dx + dy*dy + dz*dz;
        const float dd = sqrtf(d2);
        const float dinv = __builtin_amdgcn_rcpf(fmaxf(dd, 1e-12f));
        const float di2 = dinv * dinv;
        const float ax = dx * di2, ay = dy * di2, az = dz * di2;

        const float* w1r = W1 + ch * N1;      // wave-uniform -> s_load
        const float* b1r = B1 + ch * N1;
        float y1[N1];
#define L1S(o) y1[o] = tanh_fast(fmaf(dinv, w1r[o], b1r[o]));
        R25(L1S)
#undef L1S

        const float* w2r = W2 + ch * (N2 * N1);
        const float* b2r = B2 + ch * N2;
        const float* w3r = W3 + ch * (N3 * N2);
        float zf0 = B3[ch*N3+0], zf1 = B3[ch*N3+1];
        float zf2 = B3[ch*N3+2], zf3 = B3[ch*N3+3];
        float r[4];
#define MLP2I(o,i) z = fmaf(w2r[(o)*N1+(i)], y1[i], z);
#define MLP2(o) { float z = b2r[o]; R25A(MLP2I,o) \
        float y2o = tanh_fast(z) + y1[(o)%N1]; \
        if ((o) < 4) r[(o)&3] = y2o; \
        zf0 = fmaf(w3r[0*N2+(o)], y2o, zf0); \
        zf1 = fmaf(w3r[1*N2+(o)], y2o, zf1); \
        zf2 = fmaf(w3r[2*N2+(o)], y2o, zf2); \
        zf3 = fmaf(w3r[3*N2+(o)], y2o, zf3); }
        R50(MLP2)
#undef MLP2
#undef MLP2I

#define O4F(f) { float o4 = tanh_fast(f==0?zf0:f==1?zf1:f==2?zf2:zf3) + r[f]; \
        t1a[0+(f)] = fmaf(ax, o4, t1a[0+(f)]); \
        t1a[4+(f)] = fmaf(ay, o4, t1a[4+(f)]); \
        t1a[8+(f)] = fmaf(az, o4, t1a[8+(f)]); }
        O4F(0) O4F(1) O4F(2) O4F(3)
#undef O4F
    }

    float* dst = t1buf + (n * 12) * NBATCH + b;   // [n][i][b] lane-coalesced
#define TAT(i) atomicAdd(dst + (i) * NBATCH, t1a[i]);
    R12(TAT)
#undef TAT
}

// Kernel B: EXACT r11 structure (683 us proven: block=(n,gh), 512 thr, (512,4),
// i-major y2t b32 conflict-free, SGPR w35 k-pair reuse) with ONE change:
// P1 weights via wave-uniform s_load instead of LDS-staged broadcast reads.
// r13 arithmetic: r11 is LDS-issue-bound (~455 LDS insts/wave-chunk x 6 cyc x
// 16 waves ~ 44k cyc/CU/chunk vs 19k VALU); removing the 150 b128 + ~50 b32
// weight reads moves that traffic to the parallel scalar pipe (K$-hot via
// channel-uniform chunks — the ingredient r8/r9 lacked).
__global__ __launch_bounds__(512, 4) void k_res2(
    const float* __restrict__ ct, const int* __restrict__ types,
    const float* __restrict__ W1, const float* __restrict__ B1,
    const float* __restrict__ W2, const float* __restrict__ B2,
    const float* __restrict__ W3, const float* __restrict__ B3,
    const float* __restrict__ t1buf, float* __restrict__ out)
{
    __shared__ float y2t[4 * N2 * NBATCH];         // [kk][i][b] 51200 B
    __shared__ float t2s[4 * NBATCH * NAXIS];      //  4096 B
    __shared__ int   ksp[MAXKP];
    __shared__ int   chs[MAXC4];
    __shared__ int   tysh[NCH];
    __shared__ int   aux[1];

    const int n    = blockIdx.x >> 1;
    const int gh   = blockIdx.x & 1;
    const int w    = threadIdx.x >> 6;
    const int lane = threadIdx.x & 63;            // = b in both phases
    const int kk2  = w >> 1;                      // phase-1 k of chunk
    const int h    = w & 1;                       // phase-1 y2 half
    const int tid  = threadIdx.x;

    sort_pad(types, n, tysh, ksp, chs, aux, tid, 512);
    const int nch4 = __builtin_amdgcn_readfirstlane(aux[0]);

    const int tn = __builtin_amdgcn_readfirstlane(tysh[n]);

    float t1r[12];
#define T1L(i) t1r[i] = t1buf[(n*12 + (i))*NBATCH + lane];
    R12(T1L)
#undef T1L

    const int g0 = __builtin_amdgcn_readfirstlane(w * 7);   // local g within half
    int gg[7];
#define GGI(gi) gg[gi] = ((g0 + (gi)) < N2) ? (g0 + (gi)) : (N2 - 1);
    R7(GGI)
#undef GGI

    float racc[7][4];
#define RIN(gi) racc[gi][0]=0.f; racc[gi][1]=0.f; racc[gi][2]=0.f; racc[gi][3]=0.f;
    R7(RIN)
#undef RIN

    for (int kc = 0; kc < nch4; ++kc) {
        const int ch = tn * NTYPE + __builtin_amdgcn_readfirstlane(chs[kc]);
        float b3v[7];                              // wave-uniform s_load, K$-hot
#define B3L(gi) b3v[gi] = B3[ch*N3 + gh*N2 + gg[gi]];
        R7(B3L)
#undef B3L
        const int kb = kc * 4;
        // ===== phase 1: stage y2 (+t2) for 4 k's; weights via s_load =====
        {
            const int sk = __builtin_amdgcn_readfirstlane(ksp[kb + kk2]);
            if (sk >= 0) {
                const int j = (sk < n) ? sk : sk + 1;
                const float dx = ct[(n*3+0)*NBATCH + lane] - ct[(j*3+0)*NBATCH + lane];
                const float dy = ct[(n*3+1)*NBATCH + lane] - ct[(j*3+1)*NBATCH + lane];
                const float dz = ct[(n*3+2)*NBATCH + lane] - ct[(j*3+2)*NBATCH + lane];
                const float d2 = dx*dx + dy*dy + dz*dz;
                const float dd = sqrtf(d2);
                const float dinv = __builtin_amdgcn_rcpf(fmaxf(dd, 1e-12f));

                if (h == 0) {
                    const float di2 = dinv * dinv;
                    const float ax = dx * di2, ay = dy * di2, az = dz * di2;
#define T2W(f) t2s[(kk2*NBATCH + lane)*NAXIS + (f)] = \
                    ax*t1r[f] + ay*t1r[4+(f)] + az*t1r[8+(f)];
                    T2W(0) T2W(1) T2W(2) T2W(3)
#undef T2W
                }

                const float* w1r = W1 + ch * N1;   // wave-uniform -> s_load
                const float* b1r = B1 + ch * N1;
                float y1[N1];
#define L1S(o) y1[o] = tanh_fast(fmaf(dinv, w1r[o], b1r[o]));
                R25(L1S)
#undef L1S
                const int ob = h * N1;            // 0 or 25
                const float* w2h = W2 + ch * (N2*N1) + ob * N1;
                const float* b2h = B2 + ch * N2 + ob;
                float* y2w = &y2t[(kk2*N2 + ob)*NBATCH + lane];
#define P1I(oi,i) z = fmaf(w2h[(oi)*N1+(i)], y1[i], z);
#define P1S(oi) { float z = b2h[oi]; R25A(P1I,oi) \
                  y2w[(oi)*NBATCH] = tanh_fast(z) + y1[oi]; }
                R25(P1S)
#undef P1S
#undef P1I
            }
        }
        __syncthreads();
        // ===== phase 2: layer 3 + contractions (EXACT r11) =====
        const float* w3b = W3 + ch * (N3*N2) + (gh*N2) * N2;
        for (int kp = 0; kp < 2; ++kp) {
            const int skA = __builtin_amdgcn_readfirstlane(ksp[kb + kp*2 + 0]);
            const int skB = __builtin_amdgcn_readfirstlane(ksp[kb + kp*2 + 1]);
            if (skA < 0 && skB < 0) continue;
            const float* y2A = &y2t[((kp*2+0)*N2)*NBATCH + lane];
            const float* y2B = &y2t[((kp*2+1)*N2)*NBATCH + lane];
            float zA[7], zB[7];
#define ZIN(gi) zA[gi] = b3v[gi]; zB[gi] = b3v[gi];
            R7(ZIN)
#undef ZIN
            for (int ic = 0; ic < 10; ++ic) {
                const int io = ic * 5;
                float w35[7][5];                   // wave-uniform -> SGPRs
#define W35L(gi) w35[gi][0]=w3b[gg[gi]*N2+io+0]; w35[gi][1]=w3b[gg[gi]*N2+io+1]; \
                 w35[gi][2]=w3b[gg[gi]*N2+io+2]; w35[gi][3]=w3b[gg[gi]*N2+io+3]; \
                 w35[gi][4]=w3b[gg[gi]*N2+io+4];
                R7(W35L)
#undef W35L
                if (skA >= 0) {
                    float yv[5];
#define LDA(i) yv[i] = y2A[(io + (i))*NBATCH];
                    R5(LDA)
#undef LDA
#define FA(gi) zA[gi]=fmaf(w35[gi][0],yv[0],zA[gi]); zA[gi]=fmaf(w35[gi][1],yv[1],zA[gi]); \
               zA[gi]=fmaf(w35[gi][2],yv[2],zA[gi]); zA[gi]=fmaf(w35[gi][3],yv[3],zA[gi]); \
               zA[gi]=fmaf(w35[gi][4],yv[4],zA[gi]);
                    R7(FA)
#undef FA
                }
                if (skB >= 0) {
                    float yv[5];
#define LDB(i) yv[i] = y2B[(io + (i))*NBATCH];
                    R5(LDB)
#undef LDB
#define FB(gi) zB[gi]=fmaf(w35[gi][0],yv[0],zB[gi]); zB[gi]=fmaf(w35[gi][1],yv[1],zB[gi]); \
               zB[gi]=fmaf(w35[gi][2],yv[2],zB[gi]); zB[gi]=fmaf(w35[gi][3],yv[3],zB[gi]); \
               zB[gi]=fmaf(w35[gi][4],yv[4],zB[gi]);
                    R7(FB)
#undef FB
                }
            }
            if (skA >= 0) {
                const float4 t2v = *(const float4*)&t2s[((kp*2+0)*NBATCH + lane)*NAXIS];
#define PFA(gi) { float o3 = tanh_fast(zA[gi]) + y2A[gg[gi]*NBATCH]; \
                  racc[gi][0] = fmaf(o3, t2v.x, racc[gi][0]); \
                  racc[gi][1] = fmaf(o3, t2v.y, racc[gi][1]); \
                  racc[gi][2] = fmaf(o3, t2v.z, racc[gi][2]); \
                  racc[gi][3] = fmaf(o3, t2v.w, racc[gi][3]); }
                R7(PFA)
#undef PFA
            }
            if (skB >= 0) {
                const float4 t2v = *(const float4*)&t2s[((kp*2+1)*NBATCH + lane)*NAXIS];
#define PFB(gi) { float o3 = tanh_fast(zB[gi]) + y2B[gg[gi]*NBATCH]; \
                  racc[gi][0] = fmaf(o3, t2v.x, racc[gi][0]); \
                  racc[gi][1] = fmaf(o3, t2v.y, racc[gi][1]); \
                  racc[gi][2] = fmaf(o3, t2v.z, racc[gi][2]); \
                  racc[gi][3] = fmaf(o3, t2v.w, racc[gi][3]); }
                R7(PFB)
#undef PFB
            }
        }
        __syncthreads();
    }

#define PST(gi) if (g0 + (gi) < N2) { \
        float* dp = &out[(lane*NCH + n)*OUTPER + (gh*N2 + g0 + (gi))*NAXIS]; \
        atomicAdd(dp + 0, racc[gi][0]); \
        atomicAdd(dp + 1, racc[gi][1]); \
        atomicAdd(dp + 2, racc[gi][2]); \
        atomicAdd(dp + 3, racc[gi][3]); }
    R7(PST)
#undef PST
}

extern "C" void kernel_launch(void* const* d_in, const int* in_sizes, int n_in,
                              void* d_out, int out_size, void* d_ws, size_t ws_size,
                              hipStream_t stream) {
    const float* coords = (const float*)d_in[0];
    const int*   types  = (const int*)d_in[1];
    const float* W1 = (const float*)d_in[2];
    const float* B1 = (const float*)d_in[3];
    const float* W2 = (const float*)d_in[4];
    const float* B2 = (const float*)d_in[5];
    const float* W3 = (const float*)d_in[6];
    const float* B3 = (const float*)d_in[7];
    float* out = (float*)d_out;

    float* t1buf = (float*)d_ws;
    float* ct    = t1buf + NCH * 12 * NBATCH;

    hipMemsetAsync(t1buf, 0, (size_t)NCH * 12 * NBATCH * sizeof(float), stream);
    hipMemsetAsync(out, 0, (size_t)out_size * sizeof(float), stream);

    k_transpose<<<(NBATCH*NCH*3 + 255)/256, 256, 0, stream>>>(coords, ct);
    k_mlp <<<NCH*4, 256, 0, stream>>>(ct, types, W1,B1,W2,B2,W3,B3, t1buf);
    k_res2<<<NCH*2, 512, 0, stream>>>(ct, types, W1,B1,W2,B2,W3,B3, t1buf, out);
}